// Round 1
// 569.389 us; speedup vs baseline: 1.1072x; 1.1072x over previous
//
#include <hip/hip_runtime.h>
#include <cstdint>
#include <cstddef>

#define T_TOK 8192
#define C_DIM 2048
#define H_HEADS 8
#define D_HEAD 256

typedef __bf16 v8bf __attribute__((ext_vector_type(8)));
typedef float v4f __attribute__((ext_vector_type(4)));
typedef float v8f __attribute__((ext_vector_type(8)));

// Async global->LDS 16B copy. LDS dest semantics: wave-uniform base + lane*16.
__device__ __forceinline__ void async_load16(const void* gptr, void* lptr) {
    auto g = reinterpret_cast<__attribute__((address_space(1))) void*>(
        reinterpret_cast<uintptr_t>(gptr));
    auto l = reinterpret_cast<__attribute__((address_space(3))) void*>(
        static_cast<uint32_t>(reinterpret_cast<uintptr_t>(lptr)));
    __builtin_amdgcn_global_load_lds(g, l, 16, 0, 0);
}

// fp32 -> bf16, 8 elements per thread.
__global__ __launch_bounds__(256) void cvt_kernel(
    const float* __restrict__ in, __bf16* __restrict__ out)
{
    const size_t i = ((size_t)blockIdx.x * 256 + threadIdx.x) * 8;
    v8f f = *(const v8f*)&in[i];
    v8bf b;
#pragma unroll
    for (int j = 0; j < 8; ++j) b[j] = (__bf16)f[j];
    *(v8bf*)&out[i] = b;
}

// C[m,n] = sum_k A[m,k]*B[n,k] + bias[n] (+ residual[m,n]); A,B bf16, fp32 accum.
// 256x256 tile, BK=64, 512 threads (8 waves, 2x4 wave grid, 128x64 per wave).
// Double-buffered LDS (128 KiB), counted-vmcnt pipeline:
//   - raw s_barrier with lgkm-only wait mid-tile (never a full vmcnt drain)
//   - tile t+2 staged into the buffer freed at the mid-tile barrier
//   - boundary waits vmcnt(8): drains t+1's 8 loads, keeps t+2's 8 in flight
// Rotation LDS swizzle (chunk (p-row)&7) keeps ds_read_b128 conflict-free while
// global_load_lds dest stays lane-contiguous. XCD swizzle: each XCD owns an
// n-slab so its B panel stays L2-resident; requires (N/256) % 8 == 0.
template <typename OutT>
__global__ __launch_bounds__(512, 2) void gemm256_kernel(
    const __bf16* __restrict__ A, const __bf16* __restrict__ B,
    const float* __restrict__ bias, const float* __restrict__ residual,
    OutT* __restrict__ Cmat, int M, int N, int K)
{
    __shared__ __align__(16) __bf16 lds_a[2][256 * 64];  // 64 KB
    __shared__ __align__(16) __bf16 lds_b[2][256 * 64];  // 64 KB

    const int tid  = threadIdx.x;
    const int wave = tid >> 6;
    const int lane = tid & 63;
    const int lane_m = lane & 15;      // MFMA row/col within 16-tile
    const int quad   = lane >> 4;      // MFMA k-group: k = kk*32 + quad*8 + j

    // XCD-aware swizzle: xcd = id&7 (dispatch round-robin heuristic).
    // Each XCD iterates m-major over its own n-slab(s) -> B panel L2-resident.
    const int nbm = M >> 8;
    const int nbn = N >> 8;
    const int npx = nbn >> 3;          // n-blocks per XCD (1 or 2 here)
    const int bb   = blockIdx.x;
    const int xcd  = bb & 7;
    const int slot = bb >> 3;
    const int n_blk = xcd * npx + slot / nbm;
    const int m_blk = slot % nbm;
    const int block_m = m_blk << 8;
    const int block_n = n_blk << 8;

    const int wave_m = wave >> 2;      // 0..1 -> 128-row half
    const int wave_n = wave & 3;       // 0..3 -> 64-col slab

    // Per-thread staging addresses (constant except +kt) and wave-uniform LDS bases.
    const __bf16* aSrc[4];
    const __bf16* bSrc[4];
    int ldsOff[4];
#pragma unroll
    for (int r = 0; r < 4; ++r) {
        const int li  = r * 512 + tid;   // 16B chunk id, 0..2047
        const int row = li >> 3;         // tile row 0..255
        const int p   = li & 7;          // LDS chunk slot in row
        const int c   = (p - row) & 7;   // rotated global chunk
        aSrc[r] = &A[(size_t)(block_m + row) * K + c * 8];
        bSrc[r] = &B[(size_t)(block_n + row) * K + c * 8];
        ldsOff[r] = (r * 512 + wave * 64) * 8;   // wave-uniform base (elems)
    }

    auto stage = [&](int buf, int kt) {
#pragma unroll
        for (int r = 0; r < 4; ++r) {
            async_load16(aSrc[r] + kt, &lds_a[buf][ldsOff[r]]);
            async_load16(bSrc[r] + kt, &lds_b[buf][ldsOff[r]]);
        }
    };

    v4f acc[8][4];
#pragma unroll
    for (int i = 0; i < 8; ++i)
#pragma unroll
        for (int j = 0; j < 4; ++j) {
            acc[i][j][0] = 0.f; acc[i][j][1] = 0.f;
            acc[i][j][2] = 0.f; acc[i][j][3] = 0.f;
        }

    // Prologue: tiles 0 and 1 in flight; drain tile 0 only (vmcnt(8)).
    stage(0, 0);
    stage(1, 64);
    asm volatile("s_waitcnt vmcnt(8)" ::: "memory");
    __builtin_amdgcn_s_barrier();

    const int NT = K >> 6;
    int cur = 0;
    for (int t = 0; t < NT; ++t) {
        const int kt2 = (t + 2) << 6;
#pragma unroll
        for (int kk = 0; kk < 2; ++kk) {
            v8bf af[8], bfr[4];
#pragma unroll
            for (int i = 0; i < 8; ++i) {
                const int r = wave_m * 128 + i * 16 + lane_m;
                const int p = (kk * 4 + quad + r) & 7;   // inverse swizzle
                af[i] = *(const v8bf*)&lds_a[cur][r * 64 + p * 8];
            }
#pragma unroll
            for (int j = 0; j < 4; ++j) {
                const int r = wave_n * 64 + j * 16 + lane_m;
                const int p = (kk * 4 + quad + r) & 7;
                bfr[j] = *(const v8bf*)&lds_b[cur][r * 64 + p * 8];
            }
            if (kk == 1) {
                // All 24 ds_reads of buf[cur] issued; drain this wave's DS queue,
                // sync waves -> buf[cur] is free; refill it with tile t+2.
                asm volatile("s_waitcnt lgkmcnt(0)" ::: "memory");
                __builtin_amdgcn_s_barrier();
                if (t + 2 < NT) stage(cur, kt2);
            }
            __builtin_amdgcn_s_setprio(1);
#pragma unroll
            for (int i = 0; i < 8; ++i)
#pragma unroll
                for (int j = 0; j < 4; ++j)
                    acc[i][j] = __builtin_amdgcn_mfma_f32_16x16x32_bf16(
                        af[i], bfr[j], acc[i][j], 0, 0, 0);
            __builtin_amdgcn_s_setprio(0);
        }
        if (t < NT - 1) {
            if (t + 2 < NT) {
                // Drain tile t+1's 8 loads; keep tile t+2's 8 in flight.
                asm volatile("s_waitcnt vmcnt(8)" ::: "memory");
            } else {
                // Last refill already issued; full drain once at the tail.
                asm volatile("s_waitcnt vmcnt(0)" ::: "memory");
            }
            __builtin_amdgcn_s_barrier();
        }
        cur ^= 1;
    }

    // Epilogue. C/D layout: col = lane&15, row = quad*4 + reg  [verified m89]
#pragma unroll
    for (int i = 0; i < 8; ++i) {
        const int row0 = block_m + wave_m * 128 + i * 16 + quad * 4;
#pragma unroll
        for (int j = 0; j < 4; ++j) {
            const int col = block_n + wave_n * 64 + j * 16 + lane_m;
            const float bv = bias[col];
#pragma unroll
            for (int r = 0; r < 4; ++r) {
                float val = acc[i][j][r] + bv;
                const size_t off = (size_t)(row0 + r) * N + col;
                if (residual) val += residual[off];
                Cmat[off] = (OutT)val;
            }
        }
    }
}

// Per-token 8x8 attention: one wave per token, 4 tokens per 256-thread block.
// q/out stride 2048; k,v packed in kv with token stride 4096 (k at +0, v at +2048).
// out may alias q (q reads are value-dependencies of the stores).
__global__ __launch_bounds__(256) void attn_kernel(
    const __bf16* __restrict__ q, const __bf16* __restrict__ kv,
    __bf16* __restrict__ out)
{
    __shared__ __align__(16) __bf16 sq[4 * 2048];
    __shared__ __align__(16) __bf16 sk[4 * 2048];
    __shared__ __align__(16) __bf16 sv[4 * 2048];

    const int wave = threadIdx.x >> 6;
    const int lane = threadIdx.x & 63;
    const int t = blockIdx.x * 4 + wave;

    const __bf16* qt = q + (size_t)t * C_DIM;
    const __bf16* kt = kv + (size_t)t * 2 * C_DIM;
    const __bf16* vt = kt + C_DIM;
    __bf16* sqw = &sq[wave * C_DIM];
    __bf16* skw = &sk[wave * C_DIM];
    __bf16* svw = &sv[wave * C_DIM];

#pragma unroll
    for (int p = 0; p < 4; ++p) {
        const int idx = (p * 64 + lane) * 8;
        *(v8bf*)&sqw[idx] = *(const v8bf*)&qt[idx];
        *(v8bf*)&skw[idx] = *(const v8bf*)&kt[idx];
        *(v8bf*)&svw[idx] = *(const v8bf*)&vt[idx];
    }
    // all LDS traffic is wave-local: no __syncthreads needed

    const int h = lane >> 3;
    const int g = lane & 7;
    float s = 0.f;
#pragma unroll 4
    for (int d = 0; d < D_HEAD; d += 8) {
        v8bf qa = *(const v8bf*)&sqw[h * D_HEAD + d];
        v8bf ka = *(const v8bf*)&skw[g * D_HEAD + d];
#pragma unroll
        for (int jj = 0; jj < 8; ++jj) s += (float)qa[jj] * (float)ka[jj];
    }
    s *= 0.0625f;  // D^-0.5 = 1/16

    float m = s;
    m = fmaxf(m, __shfl_xor(m, 1));
    m = fmaxf(m, __shfl_xor(m, 2));
    m = fmaxf(m, __shfl_xor(m, 4));
    const float e = __expf(s - m);
    float dsum = e;
    dsum += __shfl_xor(dsum, 1);
    dsum += __shfl_xor(dsum, 2);
    dsum += __shfl_xor(dsum, 4);
    const float p_attn = e / dsum;

    float attnv[8];
#pragma unroll
    for (int gg = 0; gg < 8; ++gg)
        attnv[gg] = __shfl(p_attn, (lane & 56) | gg);

    __bf16* outp = out + (size_t)t * C_DIM + h * D_HEAD + g * 32;
    const __bf16* vbase = &svw[g * 32];
#pragma unroll
    for (int dd = 0; dd < 32; dd += 8) {
        float o[8] = {0.f, 0.f, 0.f, 0.f, 0.f, 0.f, 0.f, 0.f};
#pragma unroll
        for (int gg = 0; gg < 8; ++gg) {
            v8bf vv = *(const v8bf*)&vbase[gg * D_HEAD + dd];
            const float pg = attnv[gg];
#pragma unroll
            for (int jj = 0; jj < 8; ++jj) o[jj] += pg * (float)vv[jj];
        }
        v8bf ov;
#pragma unroll
        for (int jj = 0; jj < 8; ++jj) ov[jj] = (__bf16)o[jj];
        *(v8bf*)&outp[dd] = ov;
    }
}

extern "C" void kernel_launch(void* const* d_in, const int* in_sizes, int n_in,
                              void* d_out, int out_size, void* d_ws, size_t ws_size,
                              hipStream_t stream) {
    const float* x  = (const float*)d_in[0];
    const float* y  = (const float*)d_in[1];
    const float* Wq = (const float*)d_in[2];
    const float* bq = (const float*)d_in[3];
    const float* Wk = (const float*)d_in[4];
    const float* bk = (const float*)d_in[5];
    const float* Wv = (const float*)d_in[6];
    const float* bv = (const float*)d_in[7];
    const float* Wo = (const float*)d_in[8];
    const float* bo = (const float*)d_in[9];
    float* out = (float*)d_out;  // fp32 output

    const size_t TC = (size_t)T_TOK * C_DIM;   // 16,777,216
    const size_t CC = (size_t)C_DIM * C_DIM;   //  4,194,304

    // bf16 workspace, 4*TC + 2*CC elems (~151 MB) + 16 KB fp32 bias:
    //   [xb TC][ext TC][yb TC][q TC][Wb 2CC][bias_kv 4096 f32]
    // kv_ws overlays xb+ext (xb dead after Q-GEMM; stream order serializes).
    __bf16* xb    = (__bf16*)d_ws;
    __bf16* kv_ws = xb;                 // 2*TC, written after xb is dead
    __bf16* yb    = xb + 2 * TC;
    __bf16* q_ws  = yb + TC;
    __bf16* Wb    = q_ws + TC;          // 2*CC slot, reused sequentially
    float*  bias_kv = (float*)(Wb + 2 * CC);
    __bf16* a_ws  = q_ws;               // attn overwrites q in place

    dim3 cblock(256), gblock(512);
    const dim3 cvtTC(TC / (8 * 256)), cvtCC(CC / (8 * 256));

    cvt_kernel<<<cvtTC, cblock, 0, stream>>>(x, xb);
    cvt_kernel<<<cvtTC, cblock, 0, stream>>>(y, yb);
    hipMemcpyAsync(bias_kv,        bk, C_DIM * sizeof(float),
                   hipMemcpyDeviceToDevice, stream);
    hipMemcpyAsync(bias_kv + C_DIM, bv, C_DIM * sizeof(float),
                   hipMemcpyDeviceToDevice, stream);

    // Q = x @ Wq^T + bq
    cvt_kernel<<<cvtCC, cblock, 0, stream>>>(Wq, Wb);
    gemm256_kernel<__bf16><<<dim3((T_TOK/256)*(C_DIM/256)), gblock, 0, stream>>>(
        xb, Wb, bq, nullptr, q_ws, T_TOK, C_DIM, C_DIM);

    // [K|V] = y @ [Wk;Wv]^T + [bk;bv]   (N = 4096, overlays xb+ext)
    cvt_kernel<<<cvtCC, cblock, 0, stream>>>(Wk, Wb);
    cvt_kernel<<<cvtCC, cblock, 0, stream>>>(Wv, Wb + CC);
    gemm256_kernel<__bf16><<<dim3((T_TOK/256)*(2*C_DIM/256)), gblock, 0, stream>>>(
        yb, Wb, bias_kv, nullptr, kv_ws, T_TOK, 2 * C_DIM, C_DIM);

    attn_kernel<<<dim3(T_TOK / 4), cblock, 0, stream>>>(q_ws, kv_ws, a_ws);

    // out = attn @ Wo^T + bo + x
    cvt_kernel<<<cvtCC, cblock, 0, stream>>>(Wo, Wb);
    gemm256_kernel<float><<<dim3((T_TOK/256)*(C_DIM/256)), gblock, 0, stream>>>(
        a_ws, Wb, bo, x, out, T_TOK, C_DIM, C_DIM);
}